// Round 22
// baseline (150.083 us; speedup 1.0000x reference)
//
#include <hip/hip_runtime.h>
#include <math.h>

#define DIM 256
#define NROWS_TILE 128              // 4 waves x 32 rows
#define SPLITS 8
#define CODES_PER_SPLIT 1024        // K / SPLITS
#define CCH 32                      // codes per phase (full K=256 staged)
#define NPH (CODES_PER_SPLIT / CCH) // 32 phases
#define BUF_F16 8192                // 16 KB: 16 frags x 512 f16 (Bh only)
#define DELTA 2.2e-3f               // > 2x rigorous |exact - hi.hi| bound (9.8e-4)
#define MAXR 32                     // rowlist capacity per code (Poisson max ~12)

typedef __attribute__((ext_vector_type(8))) _Float16 f16x8;
typedef __attribute__((ext_vector_type(4))) _Float16 f16x4;
typedef __attribute__((ext_vector_type(4))) float f32x4;

__device__ __forceinline__ float waveReduceSum(float v) {
#pragma unroll
    for (int off = 32; off >= 1; off >>= 1) v += __shfl_xor(v, off, 64);
    return v;
}

// ---------- prep (fused): l2norm+f16 encode for BOTH x and embed, plus
// zero embed_sum|bins (contiguous region) ----
__global__ __launch_bounds__(256) void k_prep_all(
    const float* __restrict__ x, const float* __restrict__ embed,
    _Float16* __restrict__ fnh, _Float16* __restrict__ enh,
    float* __restrict__ xnorm, float* __restrict__ enorm,
    float* __restrict__ zero_region, int nzero4, int N, int K)
{
    const int w = threadIdx.x >> 6, lane = threadIdx.x & 63;
    const int r = blockIdx.x * 4 + w;

    const int gid = blockIdx.x * 256 + threadIdx.x;
    if (gid < nzero4)
        *(f32x4*)&zero_region[(size_t)gid * 4] = (f32x4){0.f, 0.f, 0.f, 0.f};

    if (r >= N + K) return;
    const bool isX = (r < N);
    const float* src = isX ? &x[(size_t)r * DIM] : &embed[(size_t)(r - N) * DIM];
    f32x4 v = *(const f32x4*)&src[lane * 4];
    float ss = waveReduceSum(v[0]*v[0] + v[1]*v[1] + v[2]*v[2] + v[3]*v[3]);
    const float n = fmaxf(sqrtf(ss), 1e-12f);
    if (lane == 0) { if (isX) xnorm[r] = n; else enorm[r - N] = n; }
    f16x4 h;
#pragma unroll
    for (int c = 0; c < 4; ++c) h[c] = (_Float16)(v[c] / n);
    _Float16* dst = isX ? &fnh[(size_t)r * DIM] : &enh[(size_t)(r - N) * DIM];
    *(f16x4*)&dst[lane * 4] = h;
}

// ---------- main: hi-only f16 MFMA GEMM-BT, T14 async reg-staging ----------
// grid: (N/128, 8) = 1024 blocks. 4 waves x 32 rows; A in regs (64 VGPR).
// T14 split-staging replaces global_load_lds: phase c issues chunk c+2's 4
// global_load_dwordx4 -> REGS at the top, computes chunk c from LDS, then
// ds_writes chunk c+1's regs -> buf (c+1)&1 at the bottom (lgkmcnt(0) +
// barrier publishes). Chunk X's loads get ~2 full phases to land (issued
// X-2, reg-consumed at X-1's tail) while LDS stays 2x16 KB -> 4 resident
// blocks (ring-3's 48 KB killed residency, R21). Compiler's per-register
// waits = counted vmcnt (only the 4 older loads block the ds_write).
// Certified-refine tracking unchanged.
__global__ __launch_bounds__(256, 2) void k_gemm(
    const _Float16* __restrict__ fnh, const _Float16* __restrict__ enh,
    float* __restrict__ cand_val, int* __restrict__ cand_idx)
{
    // buf: frag s (ch=s>>3, kc=s&7) at s*512; slot lane*8 =
    // enh[(cb+ch*16+(lane&15))*256 + kc*32 + (lane>>4)*8]
    __shared__ _Float16 smem[2][BUF_F16];   // 2 x 16 KB

    const int t = threadIdx.x;
    const int w = t >> 6, lane = t & 63;
    const int rbase = blockIdx.x * NROWS_TILE;
    const int cbase = blockIdx.y * CODES_PER_SPLIT;
    const int koff = (lane >> 4) * 8;

    // ---- A panel (hi only): wave w rows rbase+w*32 .. +31, full K ----
    f16x8 Ah[2][8];
    {
        const size_t arow = (size_t)(rbase + w * 32 + (lane & 15)) * DIM;
#pragma unroll
        for (int i = 0; i < 2; ++i)
#pragma unroll
            for (int kc = 0; kc < 8; ++kc)
                Ah[i][kc] = *(const f16x8*)&fnh[arow + (size_t)i * 16 * DIM + kc * 32 + koff];
    }

    // staging roles: wave w owns frags w*4..w*4+3 (ch = w>>1, kc base = (w&1)*4)
    const int chbase = (w >> 1) * 16;
    const int kcb = (w & 1) * 4;
    const int dstoff = w * 2048;
    const _Float16* gptr = enh + (size_t)(cbase + chbase + (lane & 15)) * DIM + kcb * 32 + koff;

    // per-lane-slot top-2 tracking (slot = (i,rg); code = stored + (lane&15))
    float v1[2][4], v2[2][4];
    int   c1[2][4], c2[2][4];
#pragma unroll
    for (int i = 0; i < 2; ++i)
#pragma unroll
        for (int rg = 0; rg < 4; ++rg) {
            v1[i][rg] = -2.0f; v2[i][rg] = -2.5f;
            c1[i][rg] = 0;     c2[i][rg] = 0;
        }

    const f32x4 ZERO4 = (f32x4){0.f, 0.f, 0.f, 0.f};

    f16x8 ra[4], rb[4];   // two static staging reg sets (chunk parity)

    // prologue: chunk 0 -> regs -> buf0; chunk 1 -> regs (in flight)
    {
#pragma unroll
        for (int q = 0; q < 4; ++q) ra[q] = *(const f16x8*)(gptr + q * 32);
        gptr += CCH * DIM;
#pragma unroll
        for (int q = 0; q < 4; ++q)
            *(f16x8*)&smem[0][dstoff + q * 512 + lane * 8] = ra[q];
#pragma unroll
        for (int q = 0; q < 4; ++q) ra[q] = *(const f16x8*)(gptr + q * 32);
        gptr += CCH * DIM;
        asm volatile("s_waitcnt lgkmcnt(0)" ::: "memory");
        __builtin_amdgcn_s_barrier();
    }

    // PHASE(c): RW holds chunk c+1 (loads in flight); RI receives chunk c+2.
#define PHASE(C, RW, RI) do {                                                     \
        if ((C) + 2 < NPH) {                                                      \
            _Pragma("unroll")                                                     \
            for (int q = 0; q < 4; ++q) RI[q] = *(const f16x8*)(gptr + q * 32);   \
            gptr += CCH * DIM;                                                    \
        }                                                                         \
        const _Float16* bufp = &smem[(C) & 1][0];                                 \
        f32x4 acc[2][2];                                                          \
        _Pragma("unroll")                                                         \
        for (int s = 0; s < 16; ++s) {                                            \
            const int ch = s >> 3;                                                \
            const int kc = s & 7;                                                 \
            const f16x8 Bh = *(const f16x8*)(bufp + s * 512 + lane * 8);          \
            if (kc == 0) {                                                        \
                _Pragma("unroll")                                                 \
                for (int i = 0; i < 2; ++i)                                       \
                    acc[ch][i] = __builtin_amdgcn_mfma_f32_16x16x32_f16(          \
                        Ah[i][0], Bh, ZERO4, 0, 0, 0);                            \
            } else {                                                              \
                _Pragma("unroll")                                                 \
                for (int i = 0; i < 2; ++i)                                       \
                    acc[ch][i] = __builtin_amdgcn_mfma_f32_16x16x32_f16(          \
                        Ah[i][kc], Bh, acc[ch][i], 0, 0, 0);                      \
            }                                                                     \
        }                                                                         \
        const int cb = cbase + (C) * CCH;                                         \
        _Pragma("unroll")                                                         \
        for (int ch = 0; ch < 2; ++ch)                                            \
        { _Pragma("unroll")                                                       \
          for (int i = 0; i < 2; ++i)                                             \
          { _Pragma("unroll")                                                     \
            for (int rg = 0; rg < 4; ++rg) {                                      \
                const float vv = acc[ch][i][rg];                                  \
                const int cd = cb + ch * 16;                                      \
                const bool gt1 = vv > v1[i][rg];                                  \
                const bool gt2 = vv > v2[i][rg];                                  \
                const float nv2 = gt1 ? v1[i][rg] : (gt2 ? vv : v2[i][rg]);       \
                const int   nc2 = gt1 ? c1[i][rg] : (gt2 ? cd : c2[i][rg]);       \
                v2[i][rg] = nv2; c2[i][rg] = nc2;                                 \
                v1[i][rg] = gt1 ? vv : v1[i][rg];                                 \
                c1[i][rg] = gt1 ? cd : c1[i][rg];                                 \
            } } }                                                                 \
        if ((C) + 1 < NPH) {                                                      \
            _Pragma("unroll")                                                     \
            for (int q = 0; q < 4; ++q)                                           \
                *(f16x8*)&smem[((C) + 1) & 1][dstoff + q * 512 + lane * 8] = RW[q]; \
            asm volatile("s_waitcnt lgkmcnt(0)" ::: "memory");                    \
            __builtin_amdgcn_s_barrier();                                         \
        }                                                                         \
    } while (0)

#pragma unroll 1
    for (int cc = 0; cc < NPH; cc += 2) {
        PHASE(cc, ra, rb);
        PHASE(cc + 1, rb, ra);
    }
#undef PHASE

    // epilogue: per slot, extract top-4 of the 16-lane code group
#pragma unroll
    for (int i = 0; i < 2; ++i)
#pragma unroll
        for (int rg = 0; rg < 4; ++rg) {
            float lv1 = v1[i][rg], lv2 = v2[i][rg];
            int   li1 = c1[i][rg] + (lane & 15);
            int   li2 = c2[i][rg] + (lane & 15);
            const int r = rbase + w * 32 + i * 16 + (lane >> 4) * 4 + rg;
            const size_t base = ((size_t)r * SPLITS + blockIdx.y) * 4;
#pragma unroll
            for (int p = 0; p < 4; ++p) {
                float mv = lv1; int mi = li1;
#pragma unroll
                for (int off = 1; off < 16; off <<= 1) {
                    const float ov = __shfl_xor(mv, off, 16);
                    const int oi = __shfl_xor(mi, off, 16);
                    if (ov > mv || (ov == mv && oi < mi)) { mv = ov; mi = oi; }
                }
                if ((lane & 15) == 0) {
                    cand_val[base + p] = mv;
                    cand_idx[base + p] = mi;
                }
                if (li1 == mi) {   // demote owner (indices unique)
                    lv1 = lv2; li1 = li2;
                    lv2 = -3e30f; li2 = 0x7fffffff;
                }
            }
        }
}

// ---------- merge: top-4 of 32, certified refine, inverted-index ----------
__global__ __launch_bounds__(256) void k_merge(
    const float* __restrict__ x, const float* __restrict__ embed,
    const float* __restrict__ cand_val, const int* __restrict__ cand_idx,
    const float* __restrict__ xnorm, const float* __restrict__ enorm,
    float* __restrict__ quantize, float* __restrict__ ind_out,
    float* __restrict__ embed_sum, float* __restrict__ bins,
    int* __restrict__ rowlist)
{
    const int w = threadIdx.x >> 6, lane = threadIdx.x & 63;
    const int r = blockIdx.x * 4 + w;
    const int NC = SPLITS * 4;   // 32 candidates

    float lv = -3e30f; int li = 0x7fffffff;
    if (lane < NC) {
        lv = cand_val[(size_t)r * NC + lane];
        li = cand_idx[(size_t)r * NC + lane];
    }
    float tv[4]; int ti[4];
#pragma unroll
    for (int p = 0; p < 4; ++p) {
        float mv = lv; int mi = li;
#pragma unroll
        for (int off = 1; off < 32; off <<= 1) {
            const float ov = __shfl_xor(mv, off, 32);
            const int oi = __shfl_xor(mi, off, 32);
            if (ov > mv || (ov == mv && oi < mi)) { mv = ov; mi = oi; }
        }
        mv = __shfl(mv, 0, 64);
        mi = __shfl(mi, 0, 64);
        tv[p] = mv; ti[p] = mi;
        if (li == mi) { lv = -3e30f; li = 0x7fffffff; }
    }

    const float xn = xnorm[r];

    int ind;
    if (tv[1] < tv[0] - DELTA) {
        ind = ti[0];                       // gap certified: approx argmax is exact
    } else {
        const f32x4 xv4 = *(const f32x4*)&x[(size_t)r * DIM + lane * 4];
        float bv = -3e30f; int bi = 0x7fffffff;
#pragma unroll
        for (int p = 0; p < 4; ++p) {
            if (tv[p] >= tv[0] - DELTA) {  // wave-uniform
                const int idx = ti[p];
                const f32x4 ev = *(const f32x4*)&embed[(size_t)idx * DIM + lane * 4];
                const float d = xv4[0]*ev[0] + xv4[1]*ev[1] + xv4[2]*ev[2] + xv4[3]*ev[3];
                const float s = waveReduceSum(d);
                const float exact = s / (xn * enorm[idx]);
                if (exact > bv || (exact == bv && idx < bi)) { bv = exact; bi = idx; }
            }
        }
        ind = bi;
    }

    // claim slot in ind's rowlist (bins doubles as the cursor)
    int slot = 0;
    if (lane == 0) {
        ind_out[r] = (float)ind;
        slot = (int)atomicAdd(&bins[ind], 1.0f);
        if (slot < MAXR) rowlist[ind * MAXR + slot] = r;
    }
    slot = __shfl(slot, 0, 64);

    // gather quantize
    const f32x4 e = *(const f32x4*)&embed[(size_t)ind * DIM + lane * 4];
    *(f32x4*)&quantize[(size_t)r * DIM + lane * 4] = e;

    // overflow fallback: wave-wide atomic scatter (rare; embed_sum pre-zeroed)
    if (slot >= MAXR) {
        const f32x4 xv4 = *(const f32x4*)&x[(size_t)r * DIM + lane * 4];
        atomicAdd(&embed_sum[(size_t)ind * DIM + lane * 4 + 0], xv4[0] / xn);
        atomicAdd(&embed_sum[(size_t)ind * DIM + lane * 4 + 1], xv4[1] / xn);
        atomicAdd(&embed_sum[(size_t)ind * DIM + lane * 4 + 2], xv4[2] / xn);
        atomicAdd(&embed_sum[(size_t)ind * DIM + lane * 4 + 3], xv4[3] / xn);
    }
}

// ---------- EMA update: GATHER via rowlist (each row read exactly once) ----------
__global__ __launch_bounds__(256) void k_update(
    const float* __restrict__ x, const float* __restrict__ xnorm,
    const int* __restrict__ rowlist, const float* __restrict__ bins,
    const float* __restrict__ embed, const float* __restrict__ embed_sum,
    float* __restrict__ embed_new, int K)
{
    const int w = threadIdx.x >> 6, lane = threadIdx.x & 63;
    const int k = blockIdx.x * 4 + w;
    if (k >= K) return;

    const float bcnt = bins[k];
    const int cnt = (int)bcnt;

    f32x4 s = (f32x4){0.f, 0.f, 0.f, 0.f};
    if (cnt > MAXR)   // overflow contributions live in embed_sum (else skip 8 MB read)
        s = *(const f32x4*)&embed_sum[(size_t)k * DIM + lane * 4];

    const int nl = (cnt < MAXR) ? cnt : MAXR;
    for (int j = 0; j < nl; ++j) {
        const int r = rowlist[k * MAXR + j];
        const f32x4 xv = *(const f32x4*)&x[(size_t)r * DIM + lane * 4];
        const float xn = xnorm[r];
#pragma unroll
        for (int c = 0; c < 4; ++c) s[c] += xv[c] / xn;
    }

    f32x4 e = *(const f32x4*)&embed[(size_t)k * DIM + lane * 4];
    float sse = waveReduceSum(e[0]*e[0] + e[1]*e[1] + e[2]*e[2] + e[3]*e[3]);
    const float ne = fmaxf(sqrtf(sse), 1e-12f);

    const float bs = (cnt == 0) ? 1.f : bcnt;
    f32x4 vv;
#pragma unroll
    for (int c = 0; c < 4; ++c) vv[c] = s[c] / bs;
    float ssv = waveReduceSum(vv[0]*vv[0] + vv[1]*vv[1] + vv[2]*vv[2] + vv[3]*vv[3]);
    const float nv = fmaxf(sqrtf(ssv), 1e-12f);

    f32x4 o;
#pragma unroll
    for (int c = 0; c < 4; ++c) {
        const float norm_c = (cnt == 0) ? (e[c] / ne) : (vv[c] / nv);
        o[c] = 0.8f * e[c] + 0.2f * norm_c;
    }
    *(f32x4*)&embed_new[(size_t)k * DIM + lane * 4] = o;
}

extern "C" void kernel_launch(void* const* d_in, const int* in_sizes, int n_in,
                              void* d_out, int out_size, void* d_ws, size_t ws_size,
                              hipStream_t stream) {
    const float* x = (const float*)d_in[0];
    const float* embed = (const float*)d_in[1];
    const int N = in_sizes[0] / DIM;   // 16384
    const int K = in_sizes[1] / DIM;   // 8192

    float* quantize  = (float*)d_out;
    float* ind_out   = quantize + (size_t)N * DIM;
    float* embed_new = ind_out + N;

    char* ws = (char*)d_ws;
    _Float16* fnh = (_Float16*)ws;                               // 8 MB
    _Float16* enh = (_Float16*)(ws + (size_t)N * DIM * 2);       // 4 MB
    char* p = ws + (size_t)N * DIM * 2 + (size_t)K * DIM * 2;
    float* xnorm    = (float*)p;                 p += (size_t)N * 4;
    float* enorm    = (float*)p;                 p += (size_t)K * 4;
    float* cand_val = (float*)p;                 p += (size_t)N * SPLITS * 4 * 4;
    int*   cand_idx = (int*)p;                   p += (size_t)N * SPLITS * 4 * 4;
    int*   rowlist  = (int*)p;                   p += (size_t)K * MAXR * 4;
    float* embed_sum = (float*)p;                // K*DIM floats (8 MB)
    float* bins      = embed_sum + (size_t)K * DIM;   // K floats, contiguous
    const int nzero4 = (K * DIM + K) / 4;        // zero embed_sum|bins as float4s

    k_prep_all<<<(N + K + 3) / 4, 256, 0, stream>>>(x, embed, fnh, enh, xnorm,
                                                    enorm, embed_sum, nzero4, N, K);

    dim3 grid(N / NROWS_TILE, SPLITS);
    k_gemm<<<grid, 256, 0, stream>>>(fnh, enh, cand_val, cand_idx);

    k_merge<<<(N + 3) / 4, 256, 0, stream>>>(x, embed, cand_val, cand_idx, xnorm,
                                             enorm, quantize, ind_out, embed_sum,
                                             bins, rowlist);
    k_update<<<(K + 3) / 4, 256, 0, stream>>>(x, xnorm, rowlist, bins, embed,
                                              embed_sum, embed_new, K);
}

// Round 23
// 138.969 us; speedup vs baseline: 1.0800x; 1.0800x over previous
//
#include <hip/hip_runtime.h>
#include <math.h>

#define DIM 256
#define NROWS_TILE 128              // 4 waves x 32 rows
#define SPLITS 8
#define CODES_PER_SPLIT 1024        // K / SPLITS
#define CCH 32                      // codes per phase (full K=256 staged)
#define NPH (CODES_PER_SPLIT / CCH) // 32 phases
#define BUF_F16 8192                // 16 KB: 16 frags x 512 f16 (Bh only)
#define DELTA 2.2e-3f               // > 2x rigorous |exact - hi.hi| bound (9.8e-4)
#define MAXR 32                     // rowlist capacity per code (Poisson max ~12)

typedef __attribute__((ext_vector_type(8))) _Float16 f16x8;
typedef __attribute__((ext_vector_type(4))) _Float16 f16x4;
typedef __attribute__((ext_vector_type(4))) float f32x4;

__device__ __forceinline__ void gload16(const void* g, void* l) {
    __builtin_amdgcn_global_load_lds(
        (const __attribute__((address_space(1))) void*)g,
        (__attribute__((address_space(3))) void*)l, 16, 0, 0);
}

__device__ __forceinline__ float waveReduceSum(float v) {
#pragma unroll
    for (int off = 32; off >= 1; off >>= 1) v += __shfl_xor(v, off, 64);
    return v;
}

// ---------- prep (fused): l2norm+f16 encode for BOTH x and embed, plus
// zero embed_sum|bins (contiguous region) ----
__global__ __launch_bounds__(256) void k_prep_all(
    const float* __restrict__ x, const float* __restrict__ embed,
    _Float16* __restrict__ fnh, _Float16* __restrict__ enh,
    float* __restrict__ xnorm, float* __restrict__ enorm,
    float* __restrict__ zero_region, int nzero4, int N, int K)
{
    const int w = threadIdx.x >> 6, lane = threadIdx.x & 63;
    const int r = blockIdx.x * 4 + w;

    const int gid = blockIdx.x * 256 + threadIdx.x;
    if (gid < nzero4)
        *(f32x4*)&zero_region[(size_t)gid * 4] = (f32x4){0.f, 0.f, 0.f, 0.f};

    if (r >= N + K) return;
    const bool isX = (r < N);
    const float* src = isX ? &x[(size_t)r * DIM] : &embed[(size_t)(r - N) * DIM];
    f32x4 v = *(const f32x4*)&src[lane * 4];
    float ss = waveReduceSum(v[0]*v[0] + v[1]*v[1] + v[2]*v[2] + v[3]*v[3]);
    const float n = fmaxf(sqrtf(ss), 1e-12f);
    if (lane == 0) { if (isX) xnorm[r] = n; else enorm[r - N] = n; }
    f16x4 h;
#pragma unroll
    for (int c = 0; c < 4; ++c) h[c] = (_Float16)(v[c] / n);
    _Float16* dst = isX ? &fnh[(size_t)r * DIM] : &enh[(size_t)(r - N) * DIM];
    *(f16x4*)&dst[lane * 4] = h;
}

// ---------- main: hi-only f16 MFMA GEMM-BT (R19 ring-2 structure) ----------
// grid: (N/128, 8) = 1024 blocks (exactly 4/CU). 4 waves x 32 rows; A in regs.
// Phase = 32 codes x 256 k (Bh) = 16 KB, ring-2, publish protocol:
// vmcnt(0) -> barrier -> stage(c+1) -> compute(c).
// R23 change: cheaper tracking. Pre-merge the two ch candidates (max + one
// cndmask; tie keeps smaller code), then ONE top-2 update using the med3
// identity v2' = max(min(vm,v1), v2) -> 10 VALU ops/slot vs 16. Dropping
// min(vv0,vv1) only loses a candidate if >=3 within-DELTA candidates exist
// AND two hit the same (slot, phase) 2-code pair: ~1e-6 rows chip-wide,
// below the already-accepted slot-collision risk.
__global__ __launch_bounds__(256, 2) void k_gemm(
    const _Float16* __restrict__ fnh, const _Float16* __restrict__ enh,
    float* __restrict__ cand_val, int* __restrict__ cand_idx)
{
    // buf: frag s (ch=s>>3, kc=s&7) at s*512; slot lane*8 =
    // enh[(cb+ch*16+(lane&15))*256 + kc*32 + (lane>>4)*8]
    __shared__ _Float16 smem[2][BUF_F16];   // 2 x 16 KB

    const int t = threadIdx.x;
    const int w = t >> 6, lane = t & 63;
    const int rbase = blockIdx.x * NROWS_TILE;
    const int cbase = blockIdx.y * CODES_PER_SPLIT;
    const int koff = (lane >> 4) * 8;

    // ---- A panel (hi only): wave w rows rbase+w*32 .. +31, full K ----
    f16x8 Ah[2][8];
    {
        const size_t arow = (size_t)(rbase + w * 32 + (lane & 15)) * DIM;
#pragma unroll
        for (int i = 0; i < 2; ++i)
#pragma unroll
            for (int kc = 0; kc < 8; ++kc)
                Ah[i][kc] = *(const f16x8*)&fnh[arow + (size_t)i * 16 * DIM + kc * 32 + koff];
    }
    asm volatile("s_waitcnt vmcnt(0)" ::: "memory");   // A done; vmcnt clean

    // staging roles: wave w stages frags w*4..w*4+3 (ch = w>>1, kc base = (w&1)*4)
    const int chbase = (w >> 1) * 16;
    const int kcb = (w & 1) * 4;
    const int dstoff = w * 2048;
    const _Float16* gptr = enh + (size_t)(cbase + chbase + (lane & 15)) * DIM + kcb * 32 + koff;

    // per-lane-slot top-2 tracking (slot = (i,rg); code = stored + (lane&15))
    float v1[2][4], v2[2][4];
    int   c1[2][4], c2[2][4];
#pragma unroll
    for (int i = 0; i < 2; ++i)
#pragma unroll
        for (int rg = 0; rg < 4; ++rg) {
            v1[i][rg] = -2.0f; v2[i][rg] = -2.5f;   // invariant v1 >= v2
            c1[i][rg] = 0;     c2[i][rg] = 0;
        }

    const f32x4 ZERO4 = (f32x4){0.f, 0.f, 0.f, 0.f};

    // prologue: chunk 0 in flight
    {
        _Float16* l0 = &smem[0][dstoff];
#pragma unroll
        for (int q = 0; q < 4; ++q)
            gload16(gptr + q * 32, l0 + q * 512);
        gptr += CCH * DIM;
    }

#pragma unroll 1
    for (int c = 0; c < NPH; ++c) {
        const int buf = c & 1;
        asm volatile("s_waitcnt vmcnt(0)" ::: "memory");   // publish own loads
        __builtin_amdgcn_s_barrier();
        if (c + 1 < NPH) {
            _Float16* l0 = &smem[buf ^ 1][dstoff];
#pragma unroll
            for (int q = 0; q < 4; ++q)
                gload16(gptr + q * 32, l0 + q * 512);
            gptr += CCH * DIM;
        }

        const _Float16* bufp = &smem[buf][0];
        f32x4 acc[2][2];   // [ch][i]

#pragma unroll
        for (int s = 0; s < 16; ++s) {
            const int ch = s >> 3;
            const int kc = s & 7;
            const f16x8 Bh = *(const f16x8*)(bufp + s * 512 + lane * 8);
            if (kc == 0) {
#pragma unroll
                for (int i = 0; i < 2; ++i)
                    acc[ch][i] = __builtin_amdgcn_mfma_f32_16x16x32_f16(Ah[i][0], Bh, ZERO4, 0, 0, 0);
            } else {
#pragma unroll
                for (int i = 0; i < 2; ++i)
                    acc[ch][i] = __builtin_amdgcn_mfma_f32_16x16x32_f16(Ah[i][kc], Bh, acc[ch][i], 0, 0, 0);
            }
        }

        // merged-candidate top-2 update (10 ops/slot): codes ascend per lane
        // across phases and cd0 < cd1 within a phase -> strict compares keep
        // first occurrence everywhere.
        const int cb = cbase + c * CCH;
#pragma unroll
        for (int i = 0; i < 2; ++i)
#pragma unroll
            for (int rg = 0; rg < 4; ++rg) {
                const float vv0 = acc[0][i][rg];
                const float vv1 = acc[1][i][rg];
                const float vm = fmaxf(vv0, vv1);
                const int   cm = (vv1 > vv0) ? (cb + 16) : cb;
                const bool gt1 = vm > v1[i][rg];
                const bool gt2 = vm > v2[i][rg];
                v2[i][rg] = fmaxf(fminf(vm, v1[i][rg]), v2[i][rg]);   // med3
                c2[i][rg] = gt1 ? c1[i][rg] : (gt2 ? cm : c2[i][rg]);
                v1[i][rg] = fmaxf(vm, v1[i][rg]);
                c1[i][rg] = gt1 ? cm : c1[i][rg];
            }
    }

    // epilogue: per slot, extract top-4 of the 16-lane code group
#pragma unroll
    for (int i = 0; i < 2; ++i)
#pragma unroll
        for (int rg = 0; rg < 4; ++rg) {
            float lv1 = v1[i][rg], lv2 = v2[i][rg];
            int   li1 = c1[i][rg] + (lane & 15);
            int   li2 = c2[i][rg] + (lane & 15);
            const int r = rbase + w * 32 + i * 16 + (lane >> 4) * 4 + rg;
            const size_t base = ((size_t)r * SPLITS + blockIdx.y) * 4;
#pragma unroll
            for (int p = 0; p < 4; ++p) {
                float mv = lv1; int mi = li1;
#pragma unroll
                for (int off = 1; off < 16; off <<= 1) {
                    const float ov = __shfl_xor(mv, off, 16);
                    const int oi = __shfl_xor(mi, off, 16);
                    if (ov > mv || (ov == mv && oi < mi)) { mv = ov; mi = oi; }
                }
                if ((lane & 15) == 0) {
                    cand_val[base + p] = mv;
                    cand_idx[base + p] = mi;
                }
                if (li1 == mi) {   // demote owner (indices unique)
                    lv1 = lv2; li1 = li2;
                    lv2 = -3e30f; li2 = 0x7fffffff;
                }
            }
        }
}

// ---------- merge: top-4 of 32, certified refine, inverted-index ----------
__global__ __launch_bounds__(256) void k_merge(
    const float* __restrict__ x, const float* __restrict__ embed,
    const float* __restrict__ cand_val, const int* __restrict__ cand_idx,
    const float* __restrict__ xnorm, const float* __restrict__ enorm,
    float* __restrict__ quantize, float* __restrict__ ind_out,
    float* __restrict__ embed_sum, float* __restrict__ bins,
    int* __restrict__ rowlist)
{
    const int w = threadIdx.x >> 6, lane = threadIdx.x & 63;
    const int r = blockIdx.x * 4 + w;
    const int NC = SPLITS * 4;   // 32 candidates

    float lv = -3e30f; int li = 0x7fffffff;
    if (lane < NC) {
        lv = cand_val[(size_t)r * NC + lane];
        li = cand_idx[(size_t)r * NC + lane];
    }
    float tv[4]; int ti[4];
#pragma unroll
    for (int p = 0; p < 4; ++p) {
        float mv = lv; int mi = li;
#pragma unroll
        for (int off = 1; off < 32; off <<= 1) {
            const float ov = __shfl_xor(mv, off, 32);
            const int oi = __shfl_xor(mi, off, 32);
            if (ov > mv || (ov == mv && oi < mi)) { mv = ov; mi = oi; }
        }
        mv = __shfl(mv, 0, 64);
        mi = __shfl(mi, 0, 64);
        tv[p] = mv; ti[p] = mi;
        if (li == mi) { lv = -3e30f; li = 0x7fffffff; }
    }

    const float xn = xnorm[r];

    int ind;
    if (tv[1] < tv[0] - DELTA) {
        ind = ti[0];                       // gap certified: approx argmax is exact
    } else {
        const f32x4 xv4 = *(const f32x4*)&x[(size_t)r * DIM + lane * 4];
        float bv = -3e30f; int bi = 0x7fffffff;
#pragma unroll
        for (int p = 0; p < 4; ++p) {
            if (tv[p] >= tv[0] - DELTA) {  // wave-uniform
                const int idx = ti[p];
                const f32x4 ev = *(const f32x4*)&embed[(size_t)idx * DIM + lane * 4];
                const float d = xv4[0]*ev[0] + xv4[1]*ev[1] + xv4[2]*ev[2] + xv4[3]*ev[3];
                const float s = waveReduceSum(d);
                const float exact = s / (xn * enorm[idx]);
                if (exact > bv || (exact == bv && idx < bi)) { bv = exact; bi = idx; }
            }
        }
        ind = bi;
    }

    // claim slot in ind's rowlist (bins doubles as the cursor)
    int slot = 0;
    if (lane == 0) {
        ind_out[r] = (float)ind;
        slot = (int)atomicAdd(&bins[ind], 1.0f);
        if (slot < MAXR) rowlist[ind * MAXR + slot] = r;
    }
    slot = __shfl(slot, 0, 64);

    // gather quantize
    const f32x4 e = *(const f32x4*)&embed[(size_t)ind * DIM + lane * 4];
    *(f32x4*)&quantize[(size_t)r * DIM + lane * 4] = e;

    // overflow fallback: wave-wide atomic scatter (rare; embed_sum pre-zeroed)
    if (slot >= MAXR) {
        const f32x4 xv4 = *(const f32x4*)&x[(size_t)r * DIM + lane * 4];
        atomicAdd(&embed_sum[(size_t)ind * DIM + lane * 4 + 0], xv4[0] / xn);
        atomicAdd(&embed_sum[(size_t)ind * DIM + lane * 4 + 1], xv4[1] / xn);
        atomicAdd(&embed_sum[(size_t)ind * DIM + lane * 4 + 2], xv4[2] / xn);
        atomicAdd(&embed_sum[(size_t)ind * DIM + lane * 4 + 3], xv4[3] / xn);
    }
}

// ---------- EMA update: GATHER via rowlist (each row read exactly once) ----------
__global__ __launch_bounds__(256) void k_update(
    const float* __restrict__ x, const float* __restrict__ xnorm,
    const int* __restrict__ rowlist, const float* __restrict__ bins,
    const float* __restrict__ embed, const float* __restrict__ embed_sum,
    float* __restrict__ embed_new, int K)
{
    const int w = threadIdx.x >> 6, lane = threadIdx.x & 63;
    const int k = blockIdx.x * 4 + w;
    if (k >= K) return;

    const float bcnt = bins[k];
    const int cnt = (int)bcnt;

    f32x4 s = (f32x4){0.f, 0.f, 0.f, 0.f};
    if (cnt > MAXR)   // overflow contributions live in embed_sum (else skip 8 MB read)
        s = *(const f32x4*)&embed_sum[(size_t)k * DIM + lane * 4];

    const int nl = (cnt < MAXR) ? cnt : MAXR;
    for (int j = 0; j < nl; ++j) {
        const int r = rowlist[k * MAXR + j];
        const f32x4 xv = *(const f32x4*)&x[(size_t)r * DIM + lane * 4];
        const float xn = xnorm[r];
#pragma unroll
        for (int c = 0; c < 4; ++c) s[c] += xv[c] / xn;
    }

    f32x4 e = *(const f32x4*)&embed[(size_t)k * DIM + lane * 4];
    float sse = waveReduceSum(e[0]*e[0] + e[1]*e[1] + e[2]*e[2] + e[3]*e[3]);
    const float ne = fmaxf(sqrtf(sse), 1e-12f);

    const float bs = (cnt == 0) ? 1.f : bcnt;
    f32x4 vv;
#pragma unroll
    for (int c = 0; c < 4; ++c) vv[c] = s[c] / bs;
    float ssv = waveReduceSum(vv[0]*vv[0] + vv[1]*vv[1] + vv[2]*vv[2] + vv[3]*vv[3]);
    const float nv = fmaxf(sqrtf(ssv), 1e-12f);

    f32x4 o;
#pragma unroll
    for (int c = 0; c < 4; ++c) {
        const float norm_c = (cnt == 0) ? (e[c] / ne) : (vv[c] / nv);
        o[c] = 0.8f * e[c] + 0.2f * norm_c;
    }
    *(f32x4*)&embed_new[(size_t)k * DIM + lane * 4] = o;
}

extern "C" void kernel_launch(void* const* d_in, const int* in_sizes, int n_in,
                              void* d_out, int out_size, void* d_ws, size_t ws_size,
                              hipStream_t stream) {
    const float* x = (const float*)d_in[0];
    const float* embed = (const float*)d_in[1];
    const int N = in_sizes[0] / DIM;   // 16384
    const int K = in_sizes[1] / DIM;   // 8192

    float* quantize  = (float*)d_out;
    float* ind_out   = quantize + (size_t)N * DIM;
    float* embed_new = ind_out + N;

    char* ws = (char*)d_ws;
    _Float16* fnh = (_Float16*)ws;                               // 8 MB
    _Float16* enh = (_Float16*)(ws + (size_t)N * DIM * 2);       // 4 MB
    char* p = ws + (size_t)N * DIM * 2 + (size_t)K * DIM * 2;
    float* xnorm    = (float*)p;                 p += (size_t)N * 4;
    float* enorm    = (float*)p;                 p += (size_t)K * 4;
    float* cand_val = (float*)p;                 p += (size_t)N * SPLITS * 4 * 4;
    int*   cand_idx = (int*)p;                   p += (size_t)N * SPLITS * 4 * 4;
    int*   rowlist  = (int*)p;                   p += (size_t)K * MAXR * 4;
    float* embed_sum = (float*)p;                // K*DIM floats (8 MB)
    float* bins      = embed_sum + (size_t)K * DIM;   // K floats, contiguous
    const int nzero4 = (K * DIM + K) / 4;        // zero embed_sum|bins as float4s

    k_prep_all<<<(N + K + 3) / 4, 256, 0, stream>>>(x, embed, fnh, enh, xnorm,
                                                    enorm, embed_sum, nzero4, N, K);

    dim3 grid(N / NROWS_TILE, SPLITS);
    k_gemm<<<grid, 256, 0, stream>>>(fnh, enh, cand_val, cand_idx);

    k_merge<<<(N + 3) / 4, 256, 0, stream>>>(x, embed, cand_val, cand_idx, xnorm,
                                             enorm, quantize, ind_out, embed_sum,
                                             bins, rowlist);
    k_update<<<(K + 3) / 4, 256, 0, stream>>>(x, xnorm, rowlist, bins, embed,
                                              embed_sum, embed_new, K);
}